// Round 6
// baseline (543.889 us; speedup 1.0000x reference)
//
#include <hip/hip_runtime.h>

// ResidualVQ: B=8, T=2048, D=256, Q=8, K=1024. N = B*T = 16384.
// Scoring via fp16 split-MFMA: 2x = xh + xl, e = eh + el (fp16 RTNE).
// 2x.e ~= xh.eh + xh.el + xl.eh  (dropped xl.el ~ 2e-6, below fp32 noise).
// One GEMM, reduce length 768, mapped into 512-wide packed buffers:
//   d' in [0,512):   A: ecat col d' (eh|el)    B: xcat col (d' < 256 ? d' : d'-256)
//   d' in [512,768): A: ecat col d'-512 (eh)   B: xcat col d'-256 (xl)
// score = acc - |e|^2  (row-constant |x|^2 dropped; same argmax).
//
// Score K-loop: 3-deep LDS pipeline with counted vmcnt(3) (loads span barriers)
// + T2 chunk swizzle c^=((c>>3)&3) applied as pre-swizzled global source
// (LDS dest linear, per global_load_lds constraint) + same XOR on ds_read.
//
// d_out (float): [0, N*D) quantized_out; [N*D,+Q*N) indices; [+Q) losses
// d_ws: xcat f16[N][512] | ecat f16[Q*K][512] | norms f32[Q*K] | partial float2[4][N]

typedef _Float16 f16;
typedef f16 f16x8 __attribute__((ext_vector_type(8)));
typedef float f32x4 __attribute__((ext_vector_type(4)));

constexpr int Dd = 256;
constexpr int Kk = 1024;
constexpr int Qq = 8;
constexpr int Nn = 16384;

__device__ inline void gload16(const f16* g, f16* l) {
    __builtin_amdgcn_global_load_lds(
        (const __attribute__((address_space(1))) unsigned int*)(const __attribute__((address_space(1))) f16*)g,
        (__attribute__((address_space(3))) unsigned int*)(__attribute__((address_space(3))) f16*)l,
        16, 0, 0);
}

// ---- build ecat[Q*K][512] = [eh|el] + squared norms, from fp32 codebooks ----
__global__ __launch_bounds__(256) void build_ecat(const float* __restrict__ cb,
                                                  f16* __restrict__ ecat,
                                                  float* __restrict__ norms) {
    int row = blockIdx.x * 8 + (threadIdx.x >> 5);
    int p = threadIdx.x & 31;
    const float* s = cb + (size_t)row * Dd + p * 8;
    f16x8 hi, lo;
    float sq = 0.f;
#pragma unroll
    for (int j = 0; j < 8; ++j) {
        float v = s[j];
        f16 h = (f16)v;
        hi[j] = h; lo[j] = (f16)(v - (float)h);
        sq = fmaf(v, v, sq);
    }
    *(f16x8*)(ecat + (size_t)row * 512 + p * 8) = hi;
    *(f16x8*)(ecat + (size_t)row * 512 + 256 + p * 8) = lo;
#pragma unroll
    for (int off = 16; off >= 1; off >>= 1) sq += __shfl_down(sq, off, 32);
    if (p == 0) norms[row] = sq;
}

// ---- build xcat[N][512] = [xh|xl] of 2*x (layer 0) ----
__global__ __launch_bounds__(256) void build_xcat(const float* __restrict__ src,
                                                  f16* __restrict__ xcat) {
    int row = blockIdx.x * 8 + (threadIdx.x >> 5);
    int p = threadIdx.x & 31;
    const float* s = src + (size_t)row * Dd + p * 8;
    f16x8 hi, lo;
#pragma unroll
    for (int j = 0; j < 8; ++j) {
        float v = 2.f * s[j];
        f16 h = (f16)v;
        hi[j] = h; lo[j] = (f16)(v - (float)h);
    }
    *(f16x8*)(xcat + (size_t)row * 512 + p * 8) = hi;
    *(f16x8*)(xcat + (size_t)row * 512 + 256 + p * 8) = lo;
}

// ---- scoring: block = 256-code slice x 128 tokens, 8 waves, top-1 ----
__global__ __launch_bounds__(512, 4) void score_kernel(
    const f16* __restrict__ xcat,     // [N][512]
    const f16* __restrict__ ecat,     // this layer [K][512]
    const float* __restrict__ norms,  // this layer [K]
    float2* __restrict__ partial)     // [4][N] (val, idx-as-float)
{
    __shared__ f16 tA[3][256 * 32];   // 3 x 16 KB
    __shared__ f16 tB[3][128 * 32];   // 3 x 8 KB
    __shared__ float smn[256];
    __shared__ float2 smg[4][128];

    const int tid = threadIdx.x;
    const int w = tid >> 6, l = tid & 63;
    const int wr = w >> 1, wc = w & 1;          // wr: code quad, wc: token half
    const int l16 = l & 15, hi4 = l >> 4;

    // XCD-aligned mapping: the 4 slice-blocks of one token tile share (b & 7).
    const int b = blockIdx.x;
    const int slice = (b >> 3) & 3;             // 256-code slice
    const int tokt = ((b >> 5) << 3) | (b & 7); // 128 token tiles
    const int tbase = tokt * 128;
    const int qcb = slice * 256;

    if (tid < 256) smn[tid] = norms[qcb + tid];

    // Staging: thread tid owns LDS 16B-chunk tid (tA also chunk 512+tid).
    // Swizzle swz(c) = c ^ ((c>>3)&3): LDS chunk c holds global column chunk
    // (c&3)^((c>>3)&3) of global row (c>>2). Source col pre-swizzled:
    const int srow = tid >> 2;
    const int scol = (((tid & 3) ^ ((tid >> 3) & 3))) * 8;
    const f16* ga = ecat + (size_t)(qcb + srow) * 512 + scol;
    const f16* gb = xcat + (size_t)(tbase + srow) * 512 + scol;

    // ds_read offsets with the same involution: chunk = row*4 + (hi4 ^ ((row>>1)&3))
    int offA[4], offB[4];
#pragma unroll
    for (int m = 0; m < 4; ++m) {
        int row = wr * 64 + m * 16 + l16;
        offA[m] = row * 32 + ((hi4 ^ ((row >> 1) & 3)) * 8);
    }
#pragma unroll
    for (int n = 0; n < 4; ++n) {
        int row = wc * 64 + n * 16 + l16;
        offB[n] = row * 32 + ((hi4 ^ ((row >> 1) & 3)) * 8);
    }

    f32x4 acc[4][4];
#pragma unroll
    for (int m = 0; m < 4; ++m)
#pragma unroll
        for (int n = 0; n < 4; ++n) acc[m][n] = (f32x4){0.f, 0.f, 0.f, 0.f};

#define STAGE(NB, SS) do { \
        int d0 = (SS) * 32; \
        int aoff = d0 < 512 ? d0 : d0 - 512; \
        int boff = d0 < 256 ? d0 : d0 - 256; \
        gload16(ga + aoff,             &tA[NB][tid * 8]); \
        gload16(ga + aoff + 128 * 512, &tA[NB][4096 + tid * 8]); \
        gload16(gb + boff,             &tB[NB][tid * 8]); \
    } while (0)

#define COMPUTE(CB) do { \
        f16x8 af[4], bf[4]; \
        _Pragma("unroll") for (int m = 0; m < 4; ++m) af[m] = *(const f16x8*)&tA[CB][offA[m]]; \
        _Pragma("unroll") for (int n = 0; n < 4; ++n) bf[n] = *(const f16x8*)&tB[CB][offB[n]]; \
        _Pragma("unroll") for (int m = 0; m < 4; ++m) \
        _Pragma("unroll") for (int n = 0; n < 4; ++n) \
            acc[m][n] = __builtin_amdgcn_mfma_f32_16x16x32_f16(af[m], bf[n], acc[m][n], 0, 0, 0); \
    } while (0)

    // prologue: stage steps 0,1; wait own step-0 loads (3 newest = step 1 in flight)
    STAGE(0, 0);
    STAGE(1, 1);
    asm volatile("s_waitcnt vmcnt(3)\n\ts_barrier" ::: "memory");

    // steady state: steps 0..20 (buffers rotate with period 3)
    for (int u = 0; u < 21; u += 3) {
        STAGE(2, u + 2); COMPUTE(0);
        asm volatile("s_waitcnt vmcnt(3) lgkmcnt(0)\n\ts_barrier" ::: "memory");
        STAGE(0, u + 3); COMPUTE(1);
        asm volatile("s_waitcnt vmcnt(3) lgkmcnt(0)\n\ts_barrier" ::: "memory");
        STAGE(1, u + 4); COMPUTE(2);
        asm volatile("s_waitcnt vmcnt(3) lgkmcnt(0)\n\ts_barrier" ::: "memory");
    }
    // s=21: stage last step (23), s=22 drains, s=23 computes
    STAGE(2, 23); COMPUTE(0);
    asm volatile("s_waitcnt vmcnt(3) lgkmcnt(0)\n\ts_barrier" ::: "memory");
    COMPUTE(1);
    asm volatile("s_waitcnt vmcnt(0) lgkmcnt(0)\n\ts_barrier" ::: "memory");
    COMPUTE(2);
#undef STAGE
#undef COMPUTE

    // epilogue: score = acc - |e|^2 ; top-1 (ascending code order)
    float bv[4]; int bi[4];
#pragma unroll
    for (int n = 0; n < 4; ++n) { bv[n] = -3.4e38f; bi[n] = 0; }
#pragma unroll
    for (int m = 0; m < 4; ++m) {
#pragma unroll
        for (int r = 0; r < 4; ++r) {
            int cl = wr * 64 + m * 16 + hi4 * 4 + r;   // code local in 256-slice
            float nrm = smn[cl];
            int cg = qcb + cl;
#pragma unroll
            for (int n = 0; n < 4; ++n) {
                float v = acc[m][n][r] - nrm;
                if (v > bv[n]) { bv[n] = v; bi[n] = cg; }
            }
        }
    }

    // merge across the lane>>4 groups (same token, different codes)
#pragma unroll
    for (int off = 16; off <= 32; off <<= 1) {
#pragma unroll
        for (int n = 0; n < 4; ++n) {
            float ov = __shfl_xor(bv[n], off);
            int oi = __shfl_xor(bi[n], off);
            if (ov > bv[n] || (ov == bv[n] && oi < bi[n])) { bv[n] = ov; bi[n] = oi; }
        }
    }
    if (l < 16) {
#pragma unroll
        for (int n = 0; n < 4; ++n)
            smg[wr][wc * 64 + n * 16 + l] = make_float2(bv[n], (float)bi[n]);
    }
    __syncthreads();
    // merge across the 4 code-quad waves
    if (tid < 128) {
        float2 r = smg[0][tid];
#pragma unroll
        for (int ww = 1; ww < 4; ++ww) {
            float2 c = smg[ww][tid];
            if (c.x > r.x || (c.x == r.x && c.y < r.y)) r = c;
        }
        partial[(size_t)slice * Nn + tbase + tid] = r;
    }
}

// ---- update: merge 4 partials, gather e, next xcat (or final resid), loss, idx ----
__global__ __launch_bounds__(256) void update_kernel(
    const float* __restrict__ x,       // original input (used when q==0)
    float* __restrict__ resid_out,     // d_out region (written when last==1)
    const float* __restrict__ cb,      // layer codebook [K][D] fp32
    const float2* __restrict__ partial,
    f16* __restrict__ xcat,            // read (q>0 src) and written (next layer)
    float* __restrict__ idx_out,
    float* __restrict__ loss_out,
    int q, int last)
{
    __shared__ float lsum[8];
    const int tid = threadIdx.x;
    const int row = blockIdx.x * 8 + (tid >> 5);
    const int p = tid & 31;

    float2 bsel = partial[row];
#pragma unroll
    for (int qq = 1; qq < 4; ++qq) {
        float2 c = partial[(size_t)qq * Nn + row];
        if (c.x > bsel.x || (c.x == bsel.x && c.y < bsel.y)) bsel = c;
    }
    const int k = (int)bsel.y;

    const float* e = cb + (size_t)k * Dd + p * 8;
    float rn[8];
    float lp = 0.f;
    if (q == 0) {
        const float* r = x + (size_t)row * Dd + p * 8;
#pragma unroll
        for (int j = 0; j < 8; ++j) rn[j] = r[j] - e[j];
    } else {
        f16x8 xh = *(const f16x8*)(xcat + (size_t)row * 512 + p * 8);
        f16x8 xl = *(const f16x8*)(xcat + (size_t)row * 512 + 256 + p * 8);
#pragma unroll
        for (int j = 0; j < 8; ++j) {
            float r = ((float)xh[j] + (float)xl[j]) * 0.5f;
            rn[j] = r - e[j];
        }
    }
#pragma unroll
    for (int j = 0; j < 8; ++j) lp = fmaf(rn[j], rn[j], lp);

    if (last) {
        float* ro = resid_out + (size_t)row * Dd + p * 8;
#pragma unroll
        for (int j = 0; j < 8; ++j) ro[j] = rn[j];
    } else {
        f16x8 hi2, lo2;
#pragma unroll
        for (int j = 0; j < 8; ++j) {
            float v = 2.f * rn[j];
            f16 h = (f16)v;
            hi2[j] = h; lo2[j] = (f16)(v - (float)h);
        }
        *(f16x8*)(xcat + (size_t)row * 512 + p * 8) = hi2;
        *(f16x8*)(xcat + (size_t)row * 512 + 256 + p * 8) = lo2;
    }
    if (p == 0) idx_out[row] = (float)k;

#pragma unroll
    for (int off = 16; off >= 1; off >>= 1) lp += __shfl_down(lp, off, 32);
    if (p == 0) lsum[tid >> 5] = lp;
    __syncthreads();
    if (tid == 0) {
        float s = 0.f;
#pragma unroll
        for (int i = 0; i < 8; ++i) s += lsum[i];
        atomicAdd(loss_out, s * (1.0f / ((float)Nn * (float)Dd)));
    }
}

// ---- finalize: quantized_out = x - final_residual (in place in d_out) ----
__global__ __launch_bounds__(256) void finalize_kernel(const float* __restrict__ x,
                                                       float* __restrict__ out) {
    const float4* xg = (const float4*)x;
    float4* og = (float4*)out;
    size_t n4 = (size_t)Nn * Dd / 4;
    for (size_t i = (size_t)blockIdx.x * 256 + threadIdx.x; i < n4;
         i += (size_t)gridDim.x * 256) {
        float4 a = xg[i], b2 = og[i];
        float4 o;
        o.x = a.x - b2.x; o.y = a.y - b2.y; o.z = a.z - b2.z; o.w = a.w - b2.w;
        og[i] = o;
    }
}

extern "C" void kernel_launch(void* const* d_in, const int* in_sizes, int n_in,
                              void* d_out, int out_size, void* d_ws, size_t ws_size,
                              hipStream_t stream) {
    const float* x   = (const float*)d_in[0];   // [N,D]
    const float* cbs = (const float*)d_in[1];   // [Q,K,D]
    float* out    = (float*)d_out;
    float* resid  = out;                          // final residual lives here
    float* idxs   = out + (size_t)Nn * Dd;        // [Q*N]
    float* losses = idxs + (size_t)Qq * Nn;       // [Q]

    f16* xcat    = (f16*)d_ws;                          // [N][512]
    f16* ecat    = xcat + (size_t)Nn * 512;             // [Q*K][512]
    float* norms = (float*)(ecat + (size_t)Qq * Kk * 512);  // [Q*K]
    float2* partial = (float2*)(norms + (size_t)Qq * Kk);   // [4][N]

    hipMemsetAsync(losses, 0, Qq * sizeof(float), stream);
    build_ecat<<<(Qq * Kk) / 8, 256, 0, stream>>>(cbs, ecat, norms);
    build_xcat<<<Nn / 8, 256, 0, stream>>>(x, xcat);

    for (int q = 0; q < Qq; ++q) {
        score_kernel<<<512, 512, 0, stream>>>(
            xcat, ecat + (size_t)q * Kk * 512, norms + (size_t)q * Kk, partial);
        update_kernel<<<Nn / 8, 256, 0, stream>>>(
            x, resid, cbs + (size_t)q * Kk * Dd, partial, xcat,
            idxs + (size_t)q * Nn, losses + q, q, q == Qq - 1 ? 1 : 0);
    }
    finalize_kernel<<<1024, 256, 0, stream>>>(x, out);
}